// Round 1
// baseline (567.857 us; speedup 1.0000x reference)
//
#include <hip/hip_runtime.h>
#include <math.h>

#define N_NODES 40000
#define N_EDGES 640000
#define IN_CH 128
#define HID_CH 256
#define EDGE_DIM 64
#define N_SAMP 2048
#define NSEL (1 + 2 * N_SAMP) /* 4097 selected rows: center + pos + neg */

// ---------------------------------------------------------------------------
// Edge kernel: edge_emb = edge_attr @ We + be; msg = relu(x[src] + edge_emb);
// atomic scatter-add into agg[dst]. 64 edges/block (16 per wave).
// LDS: We 32KB (shared) + per-wave attr 4KB. k-loop: 8 conflict-free b32 We
// reads + 16 broadcast b128 attr reads per 4-k step vs 128 FMAs.
// ---------------------------------------------------------------------------
__global__ __launch_bounds__(256) void edge_kernel(
    const float* __restrict__ x, const int* __restrict__ ei,
    const float* __restrict__ edge_attr, const float* __restrict__ We,
    const float* __restrict__ be, float* __restrict__ agg)
{
    __shared__ float sWe[EDGE_DIM * IN_CH];   // 32 KB
    __shared__ float sAttr[4][16 * EDGE_DIM]; // 16 KB
    const int tid = threadIdx.x;
    const int wave = tid >> 6, lane = tid & 63;

    { // stage We: 8192 floats as float4, coalesced
        const float4* s4 = (const float4*)We;
        float4* d4 = (float4*)sWe;
        for (int i = tid; i < (EDGE_DIM * IN_CH) / 4; i += 256) d4[i] = s4[i];
    }
    const int e0 = blockIdx.x * 64 + wave * 16;
    { // stage this wave's 16 attr rows (1024 floats = 256 float4), coalesced
        const float4* s4 = (const float4*)(edge_attr + (size_t)e0 * EDGE_DIM);
        float4* d4 = (float4*)sAttr[wave];
        for (int i = lane; i < 256; i += 64) d4[i] = s4[i];
    }
    __syncthreads();

    float acc0[16], acc1[16];
#pragma unroll
    for (int j = 0; j < 16; ++j) { acc0[j] = 0.f; acc1[j] = 0.f; }

    for (int k0 = 0; k0 < EDGE_DIM; k0 += 4) {
        float w0[4], w1[4];
#pragma unroll
        for (int kk = 0; kk < 4; ++kk) {
            w0[kk] = sWe[(k0 + kk) * IN_CH + lane];      // consecutive lanes ->
            w1[kk] = sWe[(k0 + kk) * IN_CH + 64 + lane]; // consecutive banks, free
        }
#pragma unroll
        for (int j = 0; j < 16; ++j) {
            float4 a = *(const float4*)&sAttr[wave][j * EDGE_DIM + k0]; // broadcast
            acc0[j] += a.x * w0[0] + a.y * w0[1] + a.z * w0[2] + a.w * w0[3];
            acc1[j] += a.x * w1[0] + a.y * w1[1] + a.z * w1[2] + a.w * w1[3];
        }
    }

    const float be0 = be[lane], be1 = be[64 + lane];
    for (int j = 0; j < 16; ++j) {
        const int e = e0 + j;
        const int s = ei[e];
        const int d = ei[N_EDGES + e];
        float m0 = x[(size_t)s * IN_CH + lane] + acc0[j] + be0;
        float m1 = x[(size_t)s * IN_CH + 64 + lane] + acc1[j] + be1;
        m0 = fmaxf(m0, 0.f);
        m1 = fmaxf(m1, 0.f);
        atomicAdd(&agg[(size_t)d * IN_CH + lane], m0);
        atomicAdd(&agg[(size_t)d * IN_CH + 64 + lane], m1);
    }
}

__device__ __forceinline__ int sel_node(int r, const int* __restrict__ pos,
                                        const int* __restrict__ neg)
{
    if (r == 0) return 0;
    if (r <= N_SAMP) return pos[r - 1];
    return neg[r - 1 - N_SAMP];
}

// ---------------------------------------------------------------------------
// MLP layer 1 on SELECTED rows only: hid[r] = relu((x[n]+agg[n]) @ W1 + b1)
// 8 rows/block, 256 threads = 256 output channels.
// ---------------------------------------------------------------------------
__global__ __launch_bounds__(256) void mlp1_kernel(
    const float* __restrict__ x, const float* __restrict__ agg,
    const int* __restrict__ pos, const int* __restrict__ neg,
    const float* __restrict__ W1, const float* __restrict__ b1,
    float* __restrict__ hid)
{
    __shared__ float sh[8][IN_CH];
    __shared__ int snode[8];
    const int tid = threadIdx.x;
    if (tid < 8) {
        int r = blockIdx.x * 8 + tid;
        snode[tid] = (r < NSEL) ? sel_node(r, pos, neg) : 0;
    }
    __syncthreads();
    for (int i = tid; i < 8 * IN_CH; i += 256) {
        int rr = i >> 7, k = i & (IN_CH - 1);
        int n = snode[rr];
        sh[rr][k] = x[(size_t)n * IN_CH + k] + agg[(size_t)n * IN_CH + k];
    }
    __syncthreads();
    float acc[8];
#pragma unroll
    for (int rr = 0; rr < 8; ++rr) acc[rr] = 0.f;
    for (int k = 0; k < IN_CH; ++k) {
        float w = W1[k * HID_CH + tid];
#pragma unroll
        for (int rr = 0; rr < 8; ++rr) acc[rr] += sh[rr][k] * w;
    }
    float bb = b1[tid];
#pragma unroll
    for (int rr = 0; rr < 8; ++rr) {
        int r = blockIdx.x * 8 + rr;
        if (r < NSEL) hid[(size_t)r * HID_CH + tid] = fmaxf(acc[rr] + bb, 0.f);
    }
}

// ---------------------------------------------------------------------------
// MLP layer 2: emb[r] = hid[r] @ W2 + b2   (no relu)
// ---------------------------------------------------------------------------
__global__ __launch_bounds__(256) void mlp2_kernel(
    const float* __restrict__ hid, const float* __restrict__ W2,
    const float* __restrict__ b2, float* __restrict__ emb)
{
    __shared__ float sh[8][HID_CH];
    const int tid = threadIdx.x;
    for (int i = tid; i < 8 * HID_CH; i += 256) {
        int rr = i >> 8, k = i & (HID_CH - 1);
        int r = blockIdx.x * 8 + rr;
        sh[rr][k] = (r < NSEL) ? hid[(size_t)r * HID_CH + k] : 0.f;
    }
    __syncthreads();
    float acc[8];
#pragma unroll
    for (int rr = 0; rr < 8; ++rr) acc[rr] = 0.f;
    for (int k = 0; k < HID_CH; ++k) {
        float w = W2[k * HID_CH + tid];
#pragma unroll
        for (int rr = 0; rr < 8; ++rr) acc[rr] += sh[rr][k] * w;
    }
    float bb = b2[tid];
#pragma unroll
    for (int rr = 0; rr < 8; ++rr) {
        int r = blockIdx.x * 8 + rr;
        if (r < NSEL) emb[(size_t)r * HID_CH + tid] = acc[rr] + bb;
    }
}

// ---------------------------------------------------------------------------
// Scores: one wave per sample row; cosine vs center (emb row 0).
// Per-block partial sums (blocks 0..511 = pos rows, 512..1023 = neg rows).
// ---------------------------------------------------------------------------
__global__ __launch_bounds__(256) void score_kernel(
    const float* __restrict__ emb, float* __restrict__ partial)
{
    const int tid = threadIdx.x;
    const int wave = tid >> 6, lane = tid & 63;
    const int rid = blockIdx.x * 4 + wave; // 0..4095
    const float4 c = ((const float4*)emb)[lane];
    const float4 v = ((const float4*)(emb + (size_t)(rid + 1) * HID_CH))[lane];
    float cc = c.x * c.x + c.y * c.y + c.z * c.z + c.w * c.w;
    float vv = v.x * v.x + v.y * v.y + v.z * v.z + v.w * v.w;
    float cv = c.x * v.x + c.y * v.y + c.z * v.z + c.w * v.w;
#pragma unroll
    for (int off = 32; off; off >>= 1) {
        cc += __shfl_xor(cc, off, 64);
        vv += __shfl_xor(vv, off, 64);
        cv += __shfl_xor(cv, off, 64);
    }
    float score = cv / (fmaxf(sqrtf(cc), 1e-12f) * fmaxf(sqrtf(vv), 1e-12f));
    __shared__ float wsum[4];
    if (lane == 0) wsum[wave] = score;
    __syncthreads();
    if (tid == 0) partial[blockIdx.x] = wsum[0] + wsum[1] + wsum[2] + wsum[3];
}

// ---------------------------------------------------------------------------
// Final loss: single wave. thr score + partial reduction + BCE.
// ---------------------------------------------------------------------------
__global__ __launch_bounds__(64) void loss_kernel(
    const float* __restrict__ emb, const float* __restrict__ thrn,
    const float* __restrict__ partial, float* __restrict__ out)
{
    const int lane = threadIdx.x;
    const float4 c = ((const float4*)emb)[lane];
    const float4 t = ((const float4*)thrn)[lane];
    float cc = c.x * c.x + c.y * c.y + c.z * c.z + c.w * c.w;
    float tt = t.x * t.x + t.y * t.y + t.z * t.z + t.w * t.w;
    float ct = c.x * t.x + c.y * t.y + c.z * t.z + c.w * t.w;
    float ps = 0.f, ns = 0.f;
#pragma unroll
    for (int i = 0; i < 8; ++i) ps += partial[lane + 64 * i];
#pragma unroll
    for (int i = 0; i < 8; ++i) ns += partial[512 + lane + 64 * i];
#pragma unroll
    for (int off = 32; off; off >>= 1) {
        cc += __shfl_xor(cc, off, 64);
        tt += __shfl_xor(tt, off, 64);
        ct += __shfl_xor(ct, off, 64);
        ps += __shfl_xor(ps, off, 64);
        ns += __shfl_xor(ns, off, 64);
    }
    if (lane == 0) {
        float thr = ct / (fmaxf(sqrtf(cc), 1e-12f) * fmaxf(sqrtf(tt), 1e-12f));
        float pm = ps / (float)N_SAMP;
        float nm = ns / (float)N_SAMP;
        float s1 = 1.f / (1.f + expf(-(pm - thr))); // T = 1.0
        float s2 = 1.f / (1.f + expf(-(thr - nm)));
        s1 = fmaxf(s1, 1e-12f);
        s2 = fmaxf(s2, 1e-12f);
        out[0] = -(logf(s1) + logf(s2));
    }
}

extern "C" void kernel_launch(void* const* d_in, const int* in_sizes, int n_in,
                              void* d_out, int out_size, void* d_ws, size_t ws_size,
                              hipStream_t stream)
{
    const float* x         = (const float*)d_in[0];
    const int*   ei        = (const int*)d_in[1];
    const float* edge_attr = (const float*)d_in[2];
    const int*   pos       = (const int*)d_in[3];
    const int*   neg       = (const int*)d_in[4];
    const float* We        = (const float*)d_in[5];
    const float* be        = (const float*)d_in[6];
    const float* W1        = (const float*)d_in[7];
    const float* b1        = (const float*)d_in[8];
    const float* W2        = (const float*)d_in[9];
    const float* b2        = (const float*)d_in[10];
    const float* thrn      = (const float*)d_in[11];
    float* out = (float*)d_out;

    float* agg     = (float*)d_ws;                     // 40000*128
    float* hid     = agg + (size_t)N_NODES * IN_CH;    // 4097*256
    float* emb     = hid + (size_t)NSEL * HID_CH;      // 4097*256
    float* partial = emb + (size_t)NSEL * HID_CH;      // 1024

    hipMemsetAsync(agg, 0, (size_t)N_NODES * IN_CH * sizeof(float), stream);
    edge_kernel<<<N_EDGES / 64, 256, 0, stream>>>(x, ei, edge_attr, We, be, agg);
    mlp1_kernel<<<(NSEL + 7) / 8, 256, 0, stream>>>(x, agg, pos, neg, W1, b1, hid);
    mlp2_kernel<<<(NSEL + 7) / 8, 256, 0, stream>>>(hid, W2, b2, emb);
    score_kernel<<<1024, 256, 0, stream>>>(emb, partial);
    loss_kernel<<<1, 64, 0, stream>>>(emb, thrn, partial, out);
}

// Round 2
// 369.933 us; speedup vs baseline: 1.5350x; 1.5350x over previous
//
#include <hip/hip_runtime.h>
#include <math.h>

#define N_NODES 40000
#define N_EDGES 640000
#define IN_CH 128
#define HID_CH 256
#define EDGE_DIM 64
#define N_SAMP 2048
#define NSEL (1 + 2 * N_SAMP) /* 4097 selected rows: center + pos + neg */
#define MAXU 4097             /* max unique selected nodes */

// ---------------------------------------------------------------------------
// Assign compact slots to selected nodes (dedup via atomicCAS).
// slot[] pre-memset to -1. counters[1] = unique-node count.
// ---------------------------------------------------------------------------
__global__ __launch_bounds__(256) void flag_kernel(
    const int* __restrict__ pos, const int* __restrict__ neg,
    int* __restrict__ slot, int* __restrict__ counters)
{
    int r = blockIdx.x * 256 + threadIdx.x;
    if (r >= NSEL) return;
    int node = (r == 0) ? 0 : (r <= N_SAMP ? pos[r - 1] : neg[r - 1 - N_SAMP]);
    int old = atomicCAS(&slot[node], -1, -2);
    if (old == -1) slot[node] = atomicAdd(&counters[1], 1);
}

// ---------------------------------------------------------------------------
// Compact edges whose dst is selected. counters[0] = surviving edge count M.
// Emits eid (attr row), esrc (source node), eslot (dst compact slot).
// ---------------------------------------------------------------------------
__global__ __launch_bounds__(256) void compact_kernel(
    const int* __restrict__ ei, const int* __restrict__ slot,
    int* __restrict__ counters, int* __restrict__ eid,
    int* __restrict__ esrc, int* __restrict__ eslot)
{
    const int tid = threadIdx.x, wave = tid >> 6, lane = tid & 63;
    const int e = blockIdx.x * 256 + tid;
    const int d = ei[N_EDGES + e];
    const int sl = slot[d];
    const bool valid = (sl >= 0);
    unsigned long long m = __ballot(valid);
    int wrank = __popcll(m & ((1ULL << lane) - 1ULL));
    __shared__ int woff[4];
    __shared__ int bbase;
    if (lane == 0) woff[wave] = __popcll(m);
    __syncthreads();
    if (tid == 0) {
        int t = 0;
        for (int i = 0; i < 4; ++i) { int c = woff[i]; woff[i] = t; t += c; }
        bbase = atomicAdd(&counters[0], t);
    }
    __syncthreads();
    if (valid) {
        int idx = bbase + woff[wave] + wrank;
        eid[idx] = e;
        esrc[idx] = ei[e];
        eslot[idx] = sl;
    }
}

// ---------------------------------------------------------------------------
// Edge kernel over COMPACTED edges: edge_emb = attr @ We + be;
// msg = relu(x[src] + edge_emb); atomicAdd into compact agg_c[slot] (~2 MB,
// L2-resident). 64 edges/block-iter (16/wave), grid-stride on M.
// ---------------------------------------------------------------------------
__global__ __launch_bounds__(256) void edge_kernel(
    const float* __restrict__ x, const float* __restrict__ edge_attr,
    const float* __restrict__ We, const float* __restrict__ be,
    const int* __restrict__ counters, const int* __restrict__ eid,
    const int* __restrict__ esrc, const int* __restrict__ eslot,
    float* __restrict__ agg_c)
{
    __shared__ float sWe[EDGE_DIM * IN_CH];   // 32 KB
    __shared__ float sAttr[4][16 * EDGE_DIM]; // 16 KB
    __shared__ int sE[4][16], sS[4][16], sL[4][16];
    const int tid = threadIdx.x, wave = tid >> 6, lane = tid & 63;
    const int M = counters[0];

    { // stage We once
        const float4* s4 = (const float4*)We;
        float4* d4 = (float4*)sWe;
        for (int i = tid; i < (EDGE_DIM * IN_CH) / 4; i += 256) d4[i] = s4[i];
    }
    __syncthreads();
    const float be0 = be[lane], be1 = be[64 + lane];

    for (int b = blockIdx.x * 64; b < M; b += gridDim.x * 64) {
        const int wb = b + wave * 16;
        if (lane < 16) {
            int idx = wb + lane;
            bool v = idx < M;
            int ic = v ? idx : 0;
            sE[wave][lane] = eid[ic];
            sS[wave][lane] = esrc[ic];
            sL[wave][lane] = v ? eslot[ic] : -1;
        }
        __syncthreads();
        { // gather 16 attr rows (256 B each, coalesced float4)
            int sub = lane >> 4, q = lane & 15;
#pragma unroll
            for (int p = 0; p < 4; ++p) {
                int j = p * 4 + sub;
                int e = sE[wave][j];
                ((float4*)&sAttr[wave][j * EDGE_DIM])[q] =
                    ((const float4*)(edge_attr + (size_t)e * EDGE_DIM))[q];
            }
        }
        __syncthreads();

        float acc0[16], acc1[16];
#pragma unroll
        for (int j = 0; j < 16; ++j) { acc0[j] = 0.f; acc1[j] = 0.f; }
        for (int k0 = 0; k0 < EDGE_DIM; k0 += 4) {
            float w0[4], w1[4];
#pragma unroll
            for (int kk = 0; kk < 4; ++kk) {
                w0[kk] = sWe[(k0 + kk) * IN_CH + lane];
                w1[kk] = sWe[(k0 + kk) * IN_CH + 64 + lane];
            }
#pragma unroll
            for (int j = 0; j < 16; ++j) {
                float4 a = *(const float4*)&sAttr[wave][j * EDGE_DIM + k0]; // broadcast
                acc0[j] += a.x * w0[0] + a.y * w0[1] + a.z * w0[2] + a.w * w0[3];
                acc1[j] += a.x * w1[0] + a.y * w1[1] + a.z * w1[2] + a.w * w1[3];
            }
        }
        for (int j = 0; j < 16; ++j) {
            int sl = sL[wave][j];
            if (sl < 0) continue;
            int s = sS[wave][j];
            float m0 = fmaxf(x[(size_t)s * IN_CH + lane] + acc0[j] + be0, 0.f);
            float m1 = fmaxf(x[(size_t)s * IN_CH + 64 + lane] + acc1[j] + be1, 0.f);
            atomicAdd(&agg_c[(size_t)sl * IN_CH + lane], m0);
            atomicAdd(&agg_c[(size_t)sl * IN_CH + 64 + lane], m1);
        }
        __syncthreads();
    }
}

// ---------------------------------------------------------------------------
// MLP layer 1 on selected rows: hid[r] = relu((x[n]+agg_c[slot[n]]) @ W1 + b1)
// 16 rows/block, 256 threads = 256 output channels.
// ---------------------------------------------------------------------------
__global__ __launch_bounds__(256) void mlp1_kernel(
    const float* __restrict__ x, const float* __restrict__ agg_c,
    const int* __restrict__ slot, const int* __restrict__ pos,
    const int* __restrict__ neg, const float* __restrict__ W1,
    const float* __restrict__ b1, float* __restrict__ hid)
{
    __shared__ float sh[16][IN_CH]; // 8 KB
    __shared__ int snode[16], sslot[16];
    const int tid = threadIdx.x;
    const int r0 = blockIdx.x * 16;
    if (tid < 16) {
        int r = r0 + tid;
        int node = 0;
        if (r < NSEL && r > 0) node = (r <= N_SAMP) ? pos[r - 1] : neg[r - 1 - N_SAMP];
        snode[tid] = node;
        sslot[tid] = slot[node]; // node 0 always has a valid slot
    }
    __syncthreads();
    for (int i = tid; i < 16 * (IN_CH / 4); i += 256) {
        int rr = i >> 5, k4 = i & 31;
        int n = snode[rr], sl = sslot[rr];
        float4 xa = ((const float4*)(x + (size_t)n * IN_CH))[k4];
        float4 ga = ((const float4*)(agg_c + (size_t)sl * IN_CH))[k4];
        ((float4*)sh[rr])[k4] =
            make_float4(xa.x + ga.x, xa.y + ga.y, xa.z + ga.z, xa.w + ga.w);
    }
    __syncthreads();
    float acc[16];
#pragma unroll
    for (int rr = 0; rr < 16; ++rr) acc[rr] = 0.f;
#pragma unroll 4
    for (int k = 0; k < IN_CH; ++k) {
        float w = W1[k * HID_CH + tid];
#pragma unroll
        for (int rr = 0; rr < 16; ++rr) acc[rr] += sh[rr][k] * w;
    }
    float bb = b1[tid];
#pragma unroll
    for (int rr = 0; rr < 16; ++rr) {
        int r = r0 + rr;
        if (r < NSEL) hid[(size_t)r * HID_CH + tid] = fmaxf(acc[rr] + bb, 0.f);
    }
}

// ---------------------------------------------------------------------------
// MLP layer 2: emb[r] = hid[r] @ W2 + b2 (no relu). 16 rows/block.
// ---------------------------------------------------------------------------
__global__ __launch_bounds__(256) void mlp2_kernel(
    const float* __restrict__ hid, const float* __restrict__ W2,
    const float* __restrict__ b2, float* __restrict__ emb)
{
    __shared__ float sh[16][HID_CH]; // 16 KB
    const int tid = threadIdx.x;
    const int r0 = blockIdx.x * 16;
    for (int i = tid; i < 16 * (HID_CH / 4); i += 256) {
        int rr = i >> 6, k4 = i & 63;
        int r = r0 + rr;
        float4 v = (r < NSEL) ? ((const float4*)(hid + (size_t)r * HID_CH))[k4]
                              : make_float4(0.f, 0.f, 0.f, 0.f);
        ((float4*)sh[rr])[k4] = v;
    }
    __syncthreads();
    float acc[16];
#pragma unroll
    for (int rr = 0; rr < 16; ++rr) acc[rr] = 0.f;
#pragma unroll 4
    for (int k = 0; k < HID_CH; ++k) {
        float w = W2[k * HID_CH + tid];
#pragma unroll
        for (int rr = 0; rr < 16; ++rr) acc[rr] += sh[rr][k] * w;
    }
    float bb = b2[tid];
#pragma unroll
    for (int rr = 0; rr < 16; ++rr) {
        int r = r0 + rr;
        if (r < NSEL) emb[(size_t)r * HID_CH + tid] = acc[rr] + bb;
    }
}

// ---------------------------------------------------------------------------
// Scores: one wave per sample row; cosine vs center (emb row 0).
// Blocks 0..511 = pos rows, 512..1023 = neg rows.
// ---------------------------------------------------------------------------
__global__ __launch_bounds__(256) void score_kernel(
    const float* __restrict__ emb, float* __restrict__ partial)
{
    const int tid = threadIdx.x;
    const int wave = tid >> 6, lane = tid & 63;
    const int rid = blockIdx.x * 4 + wave; // 0..4095
    const float4 c = ((const float4*)emb)[lane];
    const float4 v = ((const float4*)(emb + (size_t)(rid + 1) * HID_CH))[lane];
    float cc = c.x * c.x + c.y * c.y + c.z * c.z + c.w * c.w;
    float vv = v.x * v.x + v.y * v.y + v.z * v.z + v.w * v.w;
    float cv = c.x * v.x + c.y * v.y + c.z * v.z + c.w * v.w;
#pragma unroll
    for (int off = 32; off; off >>= 1) {
        cc += __shfl_xor(cc, off, 64);
        vv += __shfl_xor(vv, off, 64);
        cv += __shfl_xor(cv, off, 64);
    }
    float score = cv / (fmaxf(sqrtf(cc), 1e-12f) * fmaxf(sqrtf(vv), 1e-12f));
    __shared__ float wsum[4];
    if (lane == 0) wsum[wave] = score;
    __syncthreads();
    if (tid == 0) partial[blockIdx.x] = wsum[0] + wsum[1] + wsum[2] + wsum[3];
}

__global__ __launch_bounds__(64) void loss_kernel(
    const float* __restrict__ emb, const float* __restrict__ thrn,
    const float* __restrict__ partial, float* __restrict__ out)
{
    const int lane = threadIdx.x;
    const float4 c = ((const float4*)emb)[lane];
    const float4 t = ((const float4*)thrn)[lane];
    float cc = c.x * c.x + c.y * c.y + c.z * c.z + c.w * c.w;
    float tt = t.x * t.x + t.y * t.y + t.z * t.z + t.w * t.w;
    float ct = c.x * t.x + c.y * t.y + c.z * t.z + c.w * t.w;
    float ps = 0.f, ns = 0.f;
#pragma unroll
    for (int i = 0; i < 8; ++i) ps += partial[lane + 64 * i];
#pragma unroll
    for (int i = 0; i < 8; ++i) ns += partial[512 + lane + 64 * i];
#pragma unroll
    for (int off = 32; off; off >>= 1) {
        cc += __shfl_xor(cc, off, 64);
        tt += __shfl_xor(tt, off, 64);
        ct += __shfl_xor(ct, off, 64);
        ps += __shfl_xor(ps, off, 64);
        ns += __shfl_xor(ns, off, 64);
    }
    if (lane == 0) {
        float thr = ct / (fmaxf(sqrtf(cc), 1e-12f) * fmaxf(sqrtf(tt), 1e-12f));
        float pm = ps / (float)N_SAMP;
        float nm = ns / (float)N_SAMP;
        float s1 = 1.f / (1.f + expf(-(pm - thr)));
        float s2 = 1.f / (1.f + expf(-(thr - nm)));
        s1 = fmaxf(s1, 1e-12f);
        s2 = fmaxf(s2, 1e-12f);
        out[0] = -(logf(s1) + logf(s2));
    }
}

extern "C" void kernel_launch(void* const* d_in, const int* in_sizes, int n_in,
                              void* d_out, int out_size, void* d_ws, size_t ws_size,
                              hipStream_t stream)
{
    const float* x         = (const float*)d_in[0];
    const int*   ei        = (const int*)d_in[1];
    const float* edge_attr = (const float*)d_in[2];
    const int*   pos       = (const int*)d_in[3];
    const int*   neg       = (const int*)d_in[4];
    const float* We        = (const float*)d_in[5];
    const float* be        = (const float*)d_in[6];
    const float* W1        = (const float*)d_in[7];
    const float* b1        = (const float*)d_in[8];
    const float* W2        = (const float*)d_in[9];
    const float* b2        = (const float*)d_in[10];
    const float* thrn      = (const float*)d_in[11];
    float* out = (float*)d_out;

    int* slot     = (int*)d_ws;              // 40960 (padded)
    int* counters = slot + 40960;            // 32
    int* eid      = counters + 32;           // 640000
    int* esrc     = eid + N_EDGES;           // 640000
    int* eslot    = esrc + N_EDGES;          // 640000
    float* agg_c  = (float*)(eslot + N_EDGES);            // 4097*128 (pad 524800)
    float* hid    = agg_c + 524800;                       // 4097*256 (pad 1048832)
    float* emb    = hid + 1048832;                        // 4097*256
    float* partial= emb + 1048832;                        // 1024

    hipMemsetAsync(slot, 0xFF, 40960 * sizeof(int), stream);
    hipMemsetAsync(counters, 0, 32 * sizeof(int), stream);
    hipMemsetAsync(agg_c, 0, (size_t)MAXU * IN_CH * sizeof(float), stream);

    flag_kernel<<<(NSEL + 255) / 256, 256, 0, stream>>>(pos, neg, slot, counters);
    compact_kernel<<<N_EDGES / 256, 256, 0, stream>>>(ei, slot, counters, eid, esrc, eslot);
    edge_kernel<<<1024, 256, 0, stream>>>(x, edge_attr, We, be, counters, eid, esrc, eslot, agg_c);
    mlp1_kernel<<<(NSEL + 15) / 16, 256, 0, stream>>>(x, agg_c, slot, pos, neg, W1, b1, hid);
    mlp2_kernel<<<(NSEL + 15) / 16, 256, 0, stream>>>(hid, W2, b2, emb);
    score_kernel<<<1024, 256, 0, stream>>>(emb, partial);
    loss_kernel<<<1, 64, 0, stream>>>(emb, thrn, partial, out);
}

// Round 3
// 367.396 us; speedup vs baseline: 1.5456x; 1.0069x over previous
//
#include <hip/hip_runtime.h>
#include <math.h>

#define N_NODES 40000
#define N_EDGES 640000
#define IN_CH 128
#define HID_CH 256
#define EDGE_DIM 64
#define N_SAMP 2048
#define NSEL (1 + 2 * N_SAMP) /* 4097 selected rows */
#define MAXU 4097             /* max unique selected nodes */
#define HBUCKETS 5120         /* hist/cursor padded (1024 threads x 5) */

// ---------------------------------------------------------------------------
// Init: slot=-1, counters=0, hist=0, agg_c=0. Replaces 3 memset dispatches.
// ---------------------------------------------------------------------------
__global__ __launch_bounds__(256) void init_kernel(
    int* __restrict__ slot, int* __restrict__ counters,
    int* __restrict__ hist, float4* __restrict__ agg4)
{
    const int i = blockIdx.x * 256 + threadIdx.x;
    const int n = gridDim.x * 256;
    for (int j = i; j < 40960; j += n) slot[j] = -1;
    for (int j = i; j < HBUCKETS; j += n) hist[j] = 0;
    for (int j = i; j < 32; j += n) counters[j] = 0;
    const float4 z = make_float4(0.f, 0.f, 0.f, 0.f);
    for (int j = i; j < (MAXU * IN_CH) / 4; j += n) agg4[j] = z;
}

// ---------------------------------------------------------------------------
// Assign compact slots to selected nodes (dedup via atomicCAS).
// ---------------------------------------------------------------------------
__global__ __launch_bounds__(256) void flag_kernel(
    const int* __restrict__ pos, const int* __restrict__ neg,
    int* __restrict__ slot, int* __restrict__ counters)
{
    int r = blockIdx.x * 256 + threadIdx.x;
    if (r >= NSEL) return;
    int node = (r == 0) ? 0 : (r <= N_SAMP ? pos[r - 1] : neg[r - 1 - N_SAMP]);
    int old = atomicCAS(&slot[node], -1, -2);
    if (old == -1) slot[node] = atomicAdd(&counters[1], 1);
}

// ---------------------------------------------------------------------------
// Compact surviving edges (dst selected) into cmp[] = {attr_row, src, slot, 0}
// and build per-slot histogram. counters[0] = M.
// ---------------------------------------------------------------------------
__global__ __launch_bounds__(256) void compact_kernel(
    const int* __restrict__ ei, const int* __restrict__ slot,
    int* __restrict__ counters, int* __restrict__ hist, int4* __restrict__ cmp)
{
    const int tid = threadIdx.x, wave = tid >> 6, lane = tid & 63;
    const int e = blockIdx.x * 256 + tid;
    const int d = ei[N_EDGES + e];
    const int sl = slot[d];
    const bool valid = (sl >= 0);
    unsigned long long m = __ballot(valid);
    int wrank = __popcll(m & ((1ULL << lane) - 1ULL));
    __shared__ int woff[4];
    __shared__ int bbase;
    if (lane == 0) woff[wave] = __popcll(m);
    __syncthreads();
    if (tid == 0) {
        int t = 0;
        for (int i = 0; i < 4; ++i) { int c = woff[i]; woff[i] = t; t += c; }
        bbase = atomicAdd(&counters[0], t);
    }
    __syncthreads();
    if (valid) {
        int idx = bbase + woff[wave] + wrank;
        cmp[idx] = make_int4(e, ei[e], sl, 0);
        atomicAdd(&hist[sl], 1);
    }
}

// ---------------------------------------------------------------------------
// Exclusive scan of hist -> cursor (scatter write positions). One block.
// ---------------------------------------------------------------------------
__global__ __launch_bounds__(1024) void scan_kernel(
    const int* __restrict__ hist, int* __restrict__ cursor)
{
    __shared__ int tmp[1024];
    const int t = threadIdx.x;
    int v[5]; int s = 0;
#pragma unroll
    for (int i = 0; i < 5; ++i) { v[i] = hist[t * 5 + i]; s += v[i]; }
    tmp[t] = s;
    __syncthreads();
    for (int d = 1; d < 1024; d <<= 1) {
        int a = (t >= d) ? tmp[t - d] : 0;
        __syncthreads();
        tmp[t] += a;
        __syncthreads();
    }
    int run = tmp[t] - s; // exclusive prefix of this thread's chunk
#pragma unroll
    for (int i = 0; i < 5; ++i) { cursor[t * 5 + i] = run; run += v[i]; }
}

// ---------------------------------------------------------------------------
// Scatter compacted edges into slot-sorted order.
// ---------------------------------------------------------------------------
__global__ __launch_bounds__(256) void scatter_kernel(
    const int4* __restrict__ cmp, const int* __restrict__ counters,
    int* __restrict__ cursor, int4* __restrict__ sorted)
{
    const int M = counters[0];
    for (int i = blockIdx.x * 256 + threadIdx.x; i < M; i += gridDim.x * 256) {
        int4 c = cmp[i];
        int p = atomicAdd(&cursor[c.z], 1);
        sorted[p] = c;
    }
}

// ---------------------------------------------------------------------------
// Edge GEMM over slot-SORTED edges. 16 edges/wave per tile; register
// run-accumulation; atomicAdd only at slot-run boundaries (~2 per tile).
// ---------------------------------------------------------------------------
__global__ __launch_bounds__(256) void edge_kernel(
    const float* __restrict__ x, const float* __restrict__ edge_attr,
    const float* __restrict__ We, const float* __restrict__ be,
    const int* __restrict__ counters, const int4* __restrict__ sorted,
    float* __restrict__ agg_c)
{
    __shared__ float sWe[EDGE_DIM * IN_CH];   // 32 KB
    __shared__ float sAttr[4][16 * EDGE_DIM]; // 16 KB
    __shared__ int sE[4][16], sS[4][16], sL[4][16];
    const int tid = threadIdx.x, wave = tid >> 6, lane = tid & 63;
    const int M = counters[0];

    { // stage We once
        const float4* s4 = (const float4*)We;
        float4* d4 = (float4*)sWe;
        for (int i = tid; i < (EDGE_DIM * IN_CH) / 4; i += 256) d4[i] = s4[i];
    }
    __syncthreads();
    const float be0 = be[lane], be1 = be[64 + lane];

    for (int b = blockIdx.x * 64; b < M; b += gridDim.x * 64) {
        const int wb = b + wave * 16;
        if (lane < 16) {
            int idx = wb + lane;
            bool v = idx < M;
            int4 c = sorted[v ? idx : 0];
            sE[wave][lane] = c.x;
            sS[wave][lane] = c.y;
            sL[wave][lane] = v ? c.z : -1;
        }
        __syncthreads();
        { // gather 16 attr rows (256 B each, coalesced float4)
            int sub = lane >> 4, q = lane & 15;
#pragma unroll
            for (int p = 0; p < 4; ++p) {
                int j = p * 4 + sub;
                int e = sE[wave][j];
                ((float4*)&sAttr[wave][j * EDGE_DIM])[q] =
                    ((const float4*)(edge_attr + (size_t)e * EDGE_DIM))[q];
            }
        }
        __syncthreads();

        float acc0[16], acc1[16];
#pragma unroll
        for (int j = 0; j < 16; ++j) { acc0[j] = 0.f; acc1[j] = 0.f; }
        for (int k0 = 0; k0 < EDGE_DIM; k0 += 4) {
            float w0[4], w1[4];
#pragma unroll
            for (int kk = 0; kk < 4; ++kk) {
                w0[kk] = sWe[(k0 + kk) * IN_CH + lane];
                w1[kk] = sWe[(k0 + kk) * IN_CH + 64 + lane];
            }
#pragma unroll
            for (int j = 0; j < 16; ++j) {
                float4 a = *(const float4*)&sAttr[wave][j * EDGE_DIM + k0]; // broadcast
                acc0[j] += a.x * w0[0] + a.y * w0[1] + a.z * w0[2] + a.w * w0[3];
                acc1[j] += a.x * w1[0] + a.y * w1[1] + a.z * w1[2] + a.w * w1[3];
            }
        }

        float sum0 = 0.f, sum1 = 0.f;
#pragma unroll
        for (int j = 0; j < 16; ++j) {
            int sl = sL[wave][j];
            if (sl >= 0) {
                int s = sS[wave][j];
                float m0 = fmaxf(x[(size_t)s * IN_CH + lane] + acc0[j] + be0, 0.f);
                float m1 = fmaxf(x[(size_t)s * IN_CH + 64 + lane] + acc1[j] + be1, 0.f);
                sum0 += m0;
                sum1 += m1;
                bool flush = (j == 15) || (sL[wave][j + 1] != sl);
                if (flush) {
                    atomicAdd(&agg_c[(size_t)sl * IN_CH + lane], sum0);
                    atomicAdd(&agg_c[(size_t)sl * IN_CH + 64 + lane], sum1);
                    sum0 = 0.f;
                    sum1 = 0.f;
                }
            }
        }
        __syncthreads();
    }
}

// ---------------------------------------------------------------------------
// Fused MLP: emb[r] = relu((x[n]+agg_c[slot[n]]) @ W1 + b1) @ W2 + b2
// 16 rows/block; hid tile kept in LDS (no global round-trip).
// ---------------------------------------------------------------------------
__global__ __launch_bounds__(256) void mlp_kernel(
    const float* __restrict__ x, const float* __restrict__ agg_c,
    const int* __restrict__ slot, const int* __restrict__ pos,
    const int* __restrict__ neg, const float* __restrict__ W1,
    const float* __restrict__ b1, const float* __restrict__ W2,
    const float* __restrict__ b2, float* __restrict__ emb)
{
    __shared__ float sin_[16][IN_CH];   // 8 KB
    __shared__ float shid[16][HID_CH];  // 16 KB
    __shared__ int snode[16], sslot[16];
    const int tid = threadIdx.x;
    const int r0 = blockIdx.x * 16;
    if (tid < 16) {
        int r = r0 + tid;
        int node = 0;
        if (r < NSEL && r > 0) node = (r <= N_SAMP) ? pos[r - 1] : neg[r - 1 - N_SAMP];
        snode[tid] = node;
        sslot[tid] = slot[node];
    }
    __syncthreads();
    for (int i = tid; i < 16 * (IN_CH / 4); i += 256) {
        int rr = i >> 5, k4 = i & 31;
        int n = snode[rr], sl = sslot[rr];
        float4 xa = ((const float4*)(x + (size_t)n * IN_CH))[k4];
        float4 ga = ((const float4*)(agg_c + (size_t)sl * IN_CH))[k4];
        ((float4*)sin_[rr])[k4] =
            make_float4(xa.x + ga.x, xa.y + ga.y, xa.z + ga.z, xa.w + ga.w);
    }
    __syncthreads();

    float acc[16];
#pragma unroll
    for (int rr = 0; rr < 16; ++rr) acc[rr] = 0.f;
    for (int k0 = 0; k0 < IN_CH; k0 += 4) {
        float w[4];
#pragma unroll
        for (int kk = 0; kk < 4; ++kk) w[kk] = W1[(k0 + kk) * HID_CH + tid];
#pragma unroll
        for (int rr = 0; rr < 16; ++rr) {
            float4 h = *(const float4*)&sin_[rr][k0]; // broadcast b128
            acc[rr] += h.x * w[0] + h.y * w[1] + h.z * w[2] + h.w * w[3];
        }
    }
    float bb1 = b1[tid];
#pragma unroll
    for (int rr = 0; rr < 16; ++rr) shid[rr][tid] = fmaxf(acc[rr] + bb1, 0.f);
    __syncthreads();

#pragma unroll
    for (int rr = 0; rr < 16; ++rr) acc[rr] = 0.f;
    for (int k0 = 0; k0 < HID_CH; k0 += 4) {
        float w[4];
#pragma unroll
        for (int kk = 0; kk < 4; ++kk) w[kk] = W2[(k0 + kk) * HID_CH + tid];
#pragma unroll
        for (int rr = 0; rr < 16; ++rr) {
            float4 h = *(const float4*)&shid[rr][k0]; // broadcast b128
            acc[rr] += h.x * w[0] + h.y * w[1] + h.z * w[2] + h.w * w[3];
        }
    }
    float bb2 = b2[tid];
#pragma unroll
    for (int rr = 0; rr < 16; ++rr) {
        int r = r0 + rr;
        if (r < NSEL) emb[(size_t)r * HID_CH + tid] = acc[rr] + bb2;
    }
}

// ---------------------------------------------------------------------------
// Scores: one wave per sample row; cosine vs center (emb row 0).
// ---------------------------------------------------------------------------
__global__ __launch_bounds__(256) void score_kernel(
    const float* __restrict__ emb, float* __restrict__ partial)
{
    const int tid = threadIdx.x;
    const int wave = tid >> 6, lane = tid & 63;
    const int rid = blockIdx.x * 4 + wave; // 0..4095
    const float4 c = ((const float4*)emb)[lane];
    const float4 v = ((const float4*)(emb + (size_t)(rid + 1) * HID_CH))[lane];
    float cc = c.x * c.x + c.y * c.y + c.z * c.z + c.w * c.w;
    float vv = v.x * v.x + v.y * v.y + v.z * v.z + v.w * v.w;
    float cv = c.x * v.x + c.y * v.y + c.z * v.z + c.w * v.w;
#pragma unroll
    for (int off = 32; off; off >>= 1) {
        cc += __shfl_xor(cc, off, 64);
        vv += __shfl_xor(vv, off, 64);
        cv += __shfl_xor(cv, off, 64);
    }
    float score = cv / (fmaxf(sqrtf(cc), 1e-12f) * fmaxf(sqrtf(vv), 1e-12f));
    __shared__ float wsum[4];
    if (lane == 0) wsum[wave] = score;
    __syncthreads();
    if (tid == 0) partial[blockIdx.x] = wsum[0] + wsum[1] + wsum[2] + wsum[3];
}

__global__ __launch_bounds__(64) void loss_kernel(
    const float* __restrict__ emb, const float* __restrict__ thrn,
    const float* __restrict__ partial, float* __restrict__ out)
{
    const int lane = threadIdx.x;
    const float4 c = ((const float4*)emb)[lane];
    const float4 t = ((const float4*)thrn)[lane];
    float cc = c.x * c.x + c.y * c.y + c.z * c.z + c.w * c.w;
    float tt = t.x * t.x + t.y * t.y + t.z * t.z + t.w * t.w;
    float ct = c.x * t.x + c.y * t.y + c.z * t.z + c.w * t.w;
    float ps = 0.f, ns = 0.f;
#pragma unroll
    for (int i = 0; i < 8; ++i) ps += partial[lane + 64 * i];
#pragma unroll
    for (int i = 0; i < 8; ++i) ns += partial[512 + lane + 64 * i];
#pragma unroll
    for (int off = 32; off; off >>= 1) {
        cc += __shfl_xor(cc, off, 64);
        tt += __shfl_xor(tt, off, 64);
        ct += __shfl_xor(ct, off, 64);
        ps += __shfl_xor(ps, off, 64);
        ns += __shfl_xor(ns, off, 64);
    }
    if (lane == 0) {
        float thr = ct / (fmaxf(sqrtf(cc), 1e-12f) * fmaxf(sqrtf(tt), 1e-12f));
        float pm = ps / (float)N_SAMP;
        float nm = ns / (float)N_SAMP;
        float s1 = 1.f / (1.f + expf(-(pm - thr)));
        float s2 = 1.f / (1.f + expf(-(thr - nm)));
        s1 = fmaxf(s1, 1e-12f);
        s2 = fmaxf(s2, 1e-12f);
        out[0] = -(logf(s1) + logf(s2));
    }
}

extern "C" void kernel_launch(void* const* d_in, const int* in_sizes, int n_in,
                              void* d_out, int out_size, void* d_ws, size_t ws_size,
                              hipStream_t stream)
{
    const float* x         = (const float*)d_in[0];
    const int*   ei        = (const int*)d_in[1];
    const float* edge_attr = (const float*)d_in[2];
    const int*   pos       = (const int*)d_in[3];
    const int*   neg       = (const int*)d_in[4];
    const float* We        = (const float*)d_in[5];
    const float* be        = (const float*)d_in[6];
    const float* W1        = (const float*)d_in[7];
    const float* b1        = (const float*)d_in[8];
    const float* W2        = (const float*)d_in[9];
    const float* b2        = (const float*)d_in[10];
    const float* thrn      = (const float*)d_in[11];
    float* out = (float*)d_out;

    int* slot     = (int*)d_ws;                    // 40960
    int* counters = slot + 40960;                  // 32
    int* hist     = counters + 32;                 // 5120
    int* cursor   = hist + HBUCKETS;               // 5120
    int4* cmp     = (int4*)(cursor + HBUCKETS);    // 640000 int4 (16B-aligned)
    int4* sorted  = cmp + N_EDGES;                 // 640000 int4
    float* agg_c  = (float*)(sorted + N_EDGES);    // 4097*128 (pad 524800)
    float* emb    = agg_c + 524800;                // 4097*256
    float* partial= emb + 1048832;                 // 1024

    init_kernel<<<512, 256, 0, stream>>>(slot, counters, hist, (float4*)agg_c);
    flag_kernel<<<(NSEL + 255) / 256, 256, 0, stream>>>(pos, neg, slot, counters);
    compact_kernel<<<N_EDGES / 256, 256, 0, stream>>>(ei, slot, counters, hist, cmp);
    scan_kernel<<<1, 1024, 0, stream>>>(hist, cursor);
    scatter_kernel<<<256, 256, 0, stream>>>(cmp, counters, cursor, sorted);
    edge_kernel<<<1024, 256, 0, stream>>>(x, edge_attr, We, be, counters, sorted, agg_c);
    mlp_kernel<<<(NSEL + 15) / 16, 256, 0, stream>>>(x, agg_c, slot, pos, neg,
                                                     W1, b1, W2, b2, emb);
    score_kernel<<<1024, 256, 0, stream>>>(emb, partial);
    loss_kernel<<<1, 64, 0, stream>>>(emb, thrn, partial, out);
}